// Round 8
// baseline (360.447 us; speedup 1.0000x reference)
//
#include <hip/hip_runtime.h>
#include <hip/hip_bf16.h>
#include <math.h>

#define BN 8
#define AN 15
#define HH 100
#define WW 168
#define HW (HH*WW)           // 16800
#define NPI (AN*HW)          // 252000 scores per image
#define NTOT (BN*NPI)        // 2016000
#define PRE 2000
#define POST 1000
#define CAP 4096             // candidate buffer per image (threshold-bucket bound ~3000)
#define ROWW 32              // u64 words per NMS mask row (2000 bits -> 32 words)
#define NCHUNK 32            // ceil(PRE/64)
#define RSTRIDE 2048         // padded per-image row stride
#define EPB 4096             // elements per hist block
#define HBLK 62              // ceil(NPI/EPB)

typedef unsigned int u32;
typedef unsigned long long u64;

// ---- workspace layout (bytes) ----
#define OFF_H1     0            // 8*256*4 = 8192
#define OFF_H2     8192         // 8192
#define OFF_CSTAR  16384        // 8*128 = 1024 (cstar[b*32], base[b*32+1])
#define OFF_CCNT   17408        // 1024
#define OFF_THR    18432        // 1024
#define OFF_CAND   19456        // 8*4096*8 = 262144
#define OFF_BOX    281600       // 8*2048*16 = 262144
#define OFF_SCORE  543744       // 65536
#define OFF_VALID  609280       // 65536
#define OFF_MASK   674816       // 8*2048*32*8 = 4194304
#define OFF_DIAG   4869120      // 8*2048*8 = 131072 (packed diagonal words, ~5 MB total)
#define ZERO_WORDS ((OFF_CAND) / 4)   // only hist/counters need zeroing

__device__ __forceinline__ u32 fmono(float s) {
  u32 u = __float_as_uint(s);
  return (u & 0x80000000u) ? ~u : (u | 0x80000000u);
}
__device__ __forceinline__ float funmono(u32 m) {
  u32 u = (m & 0x80000000u) ? (m ^ 0x80000000u) : ~m;
  return __uint_as_float(u);
}
__device__ __forceinline__ float areaf(float4 bx) {
  return __fmul_rn(__fadd_rn(__fsub_rn(bx.z, bx.x), 1.0f),
                   __fadd_rn(__fsub_rn(bx.w, bx.y), 1.0f));
}

__global__ void zero_kernel(u32* p, int n) {
  int i = blockIdx.x * blockDim.x + threadIdx.x;
  if (i < n) p[i] = 0u;
}

// phase-1 histogram: 256 coarse buckets (m>>24), LDS-privatized 4-way
__global__ __launch_bounds__(256) void hist1_kernel(const float* __restrict__ cls,
                                                    u32* __restrict__ h1) {
  __shared__ u32 lh[1024];   // 4 copies x 256 buckets
  int b = blockIdx.y;
  int t = threadIdx.x;
  for (int q = t; q < 1024; q += 256) lh[q] = 0u;
  __syncthreads();
  int start = blockIdx.x * EPB;
  int end = min(start + EPB, NPI);
  const float* p = cls + (size_t)b * NPI;
  u32 copy = ((u32)t & 3u) << 8;
  for (int i = start + t; i < end; i += 256) {
    u32 m = fmono(p[i]);
    atomicAdd(&lh[copy | (m >> 24)], 1u);
  }
  __syncthreads();
  u32 s = lh[t] + lh[t + 256] + lh[t + 512] + lh[t + 768];
  if (s) atomicAdd(&h1[(b << 8) + t], s);
}

// pick coarse bucket c*: suffix scan of 256 coarse counts
__global__ __launch_bounds__(256) void coarse_kernel(const u32* __restrict__ h1,
                                                     u32* __restrict__ cstar) {
  int b = blockIdx.x;
  int t = threadIdx.x;
  __shared__ u32 sfx[256];
  sfx[t] = h1[(b << 8) + t];
  __syncthreads();
  for (int d = 1; d < 256; d <<= 1) {
    u32 add = (t + d < 256) ? sfx[t + d] : 0u;
    __syncthreads();
    sfx[t] += add;
    __syncthreads();
  }
  if (t == 0 && sfx[0] < (u32)PRE) { cstar[b * 32] = 0u; cstar[b * 32 + 1] = sfx[1]; }
  if (sfx[t] >= (u32)PRE && (t == 255 || sfx[t + 1] < (u32)PRE)) {
    cstar[b * 32] = (u32)t;
    cstar[b * 32 + 1] = (t == 255) ? 0u : sfx[t + 1];   // count strictly above c*
  }
}

// phase-2 histogram: 256 fine buckets ((m>>16)&0xFF), filtered to m>>24==c*
__global__ __launch_bounds__(256) void hist2_kernel(const float* __restrict__ cls,
                                                    const u32* __restrict__ cstar,
                                                    u32* __restrict__ h2) {
  __shared__ u32 lh[256];
  int b = blockIdx.y;
  int t = threadIdx.x;
  lh[t] = 0u;
  __syncthreads();
  u32 cs = cstar[b * 32];
  int start = blockIdx.x * EPB;
  int end = min(start + EPB, NPI);
  const float* p = cls + (size_t)b * NPI;
  for (int i = start + t; i < end; i += 256) {
    u32 m = fmono(p[i]);
    if ((m >> 24) == cs) atomicAdd(&lh[(m >> 16) & 0xFFu], 1u);
  }
  __syncthreads();
  if (lh[t]) atomicAdd(&h2[(b << 8) + t], lh[t]);
}

// final 16-bit threshold: thr16 = (c*<<8) | k*, largest k with base+sfx[k] >= PRE
__global__ __launch_bounds__(256) void fine_kernel(const u32* __restrict__ h2,
                                                   const u32* __restrict__ cstar,
                                                   u32* __restrict__ thr) {
  int b = blockIdx.x;
  int t = threadIdx.x;
  __shared__ u32 sfx[256];
  sfx[t] = h2[(b << 8) + t];
  __syncthreads();
  for (int d = 1; d < 256; d <<= 1) {
    u32 add = (t + d < 256) ? sfx[t + d] : 0u;
    __syncthreads();
    sfx[t] += add;
    __syncthreads();
  }
  u32 cs = cstar[b * 32], base = cstar[b * 32 + 1];
  if (t == 0 && base + sfx[0] < (u32)PRE) thr[b * 32] = (cs << 8);
  if (base + sfx[t] >= (u32)PRE && (t == 255 || base + sfx[t + 1] < (u32)PRE))
    thr[b * 32] = (cs << 8) | (u32)t;
}

// wave-aggregated gather: one atomic per wave with >=1 candidate
__global__ void gather_kernel(const float* __restrict__ cls, const u32* __restrict__ thr,
                              u32* __restrict__ ccnt, u64* __restrict__ cand) {
  int tid = blockIdx.x * blockDim.x + threadIdx.x;   // grid exactly covers NTOT
  int b = tid / NPI;
  int r = tid - b * NPI;
  u32 m = fmono(cls[tid]);
  bool pass = (m >> 16) >= thr[b * 32];
  int lane = threadIdx.x & 63;
  int b0 = __shfl(b, 0, 64);
  bool uni = (__ballot(b != b0) == 0ULL);
  u32 pos = 0xffffffffu;
  if (uni) {
    u64 bal = __ballot(pass);
    if (bal) {
      int leader = __ffsll((long long)bal) - 1;
      u32 base = 0;
      if (lane == leader) base = atomicAdd(&ccnt[b * 32], (u32)__popcll(bal));
      base = __shfl(base, leader, 64);
      if (pass) pos = base + (u32)__popcll(bal & ((1ULL << lane) - 1ULL));
    }
  } else if (pass) {
    pos = atomicAdd(&ccnt[b * 32], 1u);
  }
  if (pass && pos < CAP) {
    int a  = r / HW;
    int hw = r - a * HW;
    u32 i  = (u32)(hw * AN + a);   // transposed flat index (h*W + w)*A + a
    cand[(size_t)b * CAP + pos] = ((u64)m << 32) | (u32)(~i);
  }
}

__global__ __launch_bounds__(1024) void sort_transform_kernel(
    const u64* __restrict__ cand, const u32* __restrict__ ccnt,
    const float* __restrict__ bbox, const float* __restrict__ iminfo,
    const float* __restrict__ anch,
    float4* __restrict__ boxes, float* __restrict__ scores, int* __restrict__ valid) {
  __shared__ u64 keys[CAP];   // 32 KB
  int b = blockIdx.x;
  int t = threadIdx.x;
  u32 cnt = ccnt[b * 32];
  if (cnt > CAP) cnt = CAP;
  for (int q = t; q < CAP; q += 1024) keys[q] = (q < (int)cnt) ? cand[(size_t)b * CAP + q] : 0ULL;
  __syncthreads();
  // bitonic sort, descending
  for (u32 k = 2; k <= CAP; k <<= 1) {
    for (u32 j = k >> 1; j > 0; j >>= 1) {
      for (int p = 0; p < CAP / 2 / 1024; ++p) {
        u32 idx = (u32)t + (u32)p * 1024u;           // 0..CAP/2-1
        u32 base = ((idx & ~(j - 1)) << 1) | (idx & (j - 1));
        u32 partner = base + j;
        bool up = ((base & k) == 0);
        u64 A = keys[base], B = keys[partner];
        bool sw = up ? (A < B) : (A > B);
        if (sw) { keys[base] = B; keys[partner] = A; }
      }
      __syncthreads();
    }
  }
  // transform the top PRE
  float im_h = iminfo[b * 3 + 0], im_w = iminfo[b * 3 + 1], im_s = iminfo[b * 3 + 2];
  float wmax = __fsub_rn(im_w, 1.0f), hmax = __fsub_rn(im_h, 1.0f);
  float msz = __fmul_rn(0.0f, im_s);
  const float BCLIP = (float)4.135166556742356;  // log(1000/16)
  for (int q = t; q < PRE; q += 1024) {
    u64 key = keys[q];
    u32 i = ~((u32)key);
    // defensive: pad keys (q >= cnt) decode to i >= NPI -> never dereference
    if (q >= (int)cnt || i >= (u32)NPI) {
      boxes[b * RSTRIDE + q] = make_float4(0.f, 0.f, 0.f, 0.f);
      scores[b * RSTRIDE + q] = 0.f;
      valid[b * RSTRIDE + q] = 0;
      continue;
    }
    float sc = funmono((u32)(key >> 32));
    int a = (int)(i % AN);
    int pp = (int)(i / AN);
    int w = pp % WW;
    int h = pp / WW;
    float sx = (float)(w * 8), sy = (float)(h * 8);
    float ax1 = __fadd_rn(anch[a * 4 + 0], sx);
    float ay1 = __fadd_rn(anch[a * 4 + 1], sy);
    float ax2 = __fadd_rn(anch[a * 4 + 2], sx);
    float ay2 = __fadd_rn(anch[a * 4 + 3], sy);
    float wsA = __fadd_rn(__fsub_rn(ax2, ax1), 1.0f);
    float hsA = __fadd_rn(__fsub_rn(ay2, ay1), 1.0f);
    float cx = __fadd_rn(ax1, __fmul_rn(0.5f, wsA));
    float cy = __fadd_rn(ay1, __fmul_rn(0.5f, hsA));
    const float* dp = bbox + ((size_t)b * (4 * AN) + 4 * a) * HW + (size_t)h * WW + w;
    float dx = dp[0], dy = dp[HW], dwv = dp[2 * HW], dhv = dp[3 * HW];
    dwv = fminf(dwv, BCLIP);
    dhv = fminf(dhv, BCLIP);
    float pcx = __fadd_rn(__fmul_rn(dx, wsA), cx);
    float pcy = __fadd_rn(__fmul_rn(dy, hsA), cy);
    float pw = __fmul_rn((float)exp((double)dwv), wsA);
    float ph = __fmul_rn((float)exp((double)dhv), hsA);
    float hpw = __fmul_rn(0.5f, pw), hph = __fmul_rn(0.5f, ph);
    float x1 = __fsub_rn(pcx, hpw);
    float y1 = __fsub_rn(pcy, hph);
    float x2 = __fsub_rn(__fadd_rn(pcx, hpw), 1.0f);
    float y2 = __fsub_rn(__fadd_rn(pcy, hph), 1.0f);
    x1 = fminf(fmaxf(x1, 0.0f), wmax);
    y1 = fminf(fmaxf(y1, 0.0f), hmax);
    x2 = fminf(fmaxf(x2, 0.0f), wmax);
    y2 = fminf(fmaxf(y2, 0.0f), hmax);
    float ws2 = __fadd_rn(__fsub_rn(x2, x1), 1.0f);
    float hs2 = __fadd_rn(__fsub_rn(y2, y1), 1.0f);
    int v = (ws2 >= msz) && (hs2 >= msz) &&
            (__fadd_rn(x1, __fmul_rn(ws2, 0.5f)) < im_w) &&
            (__fadd_rn(y1, __fmul_rn(hs2, 0.5f)) < im_h);
    boxes[b * RSTRIDE + q] = make_float4(x1, y1, x2, y2);
    scores[b * RSTRIDE + q] = sc;
    valid[b * RSTRIDE + q] = v;
  }
}

__global__ __launch_bounds__(64) void nms_mask_kernel(const float4* __restrict__ boxes,
                                                      u64* __restrict__ mask,
                                                      u64* __restrict__ diag) {
  int jb = blockIdx.x, ib = blockIdx.y, b = blockIdx.z;
  if (jb < ib) return;   // upper triangle only (j > i needed)
  int t = threadIdx.x;
  __shared__ float4 jbox[64];
  __shared__ float jarea[64];
  int jbase = jb * 64;
  int jcount = min(64, PRE - jbase);
  if (t < jcount) {
    float4 bj = boxes[b * RSTRIDE + jbase + t];
    jbox[t] = bj;
    jarea[t] = areaf(bj);
  }
  __syncthreads();
  int i = ib * 64 + t;
  if (i >= PRE) return;
  float4 bi = boxes[b * RSTRIDE + i];
  float ai = areaf(bi);
  u64 word = 0ULL;
  for (int jj = 0; jj < jcount; ++jj) {
    int j = jbase + jj;
    if (j <= i) continue;
    float4 bj = jbox[jj];
    float iw = fmaxf(__fadd_rn(__fsub_rn(fminf(bi.z, bj.z), fmaxf(bi.x, bj.x)), 1.0f), 0.0f);
    float ih = fmaxf(__fadd_rn(__fsub_rn(fminf(bi.w, bj.w), fmaxf(bi.y, bj.y)), 1.0f), 0.0f);
    float inter = __fmul_rn(iw, ih);
    float denom = __fsub_rn(__fadd_rn(ai, jarea[jj]), inter);
    float iou = inter / denom;
    if (iou > 0.7f) word |= (1ULL << jj);
  }
  mask[((size_t)(b * RSTRIDE) + i) * ROWW + jb] = word;
  if (jb == ib) diag[(size_t)b * RSTRIDE + i] = word;   // packed diagonal word
}

// ---------------- seq NMS v5: scalar-pipe serial chain ------------------
// R7 postmortem: bpermute traffic (256/chunk) was the cost, not spills.
// The chain consumes only wave-uniform data (cur, vb=ballot, diag words),
// so it now runs on SALU: diag words read via a uniform pointer with the
// ii-loop fully unrolled -> s_load_dwordx16 batches; chain = s_cselect_b64/
// s_or_b64 (~4cyc/step, co-issues with VALU fold). Crosslane ops reduced to
// 1 ballot + 4 readlanes per chunk.
template <int C>
__device__ __forceinline__ void nms_chunk(
    const u64* __restrict__ base, const u64* __restrict__ dg,
    u64 (&Rt)[32], u64 (&Pt)[32], u64 vb, u64& rem, u64& cur,
    u64* __restrict__ kbits_s, int lane, int lw, int hf) {
  // prefetch next chunk's tile (independent of everything below)
  if (C + 1 < NCHUNK) {
    const u64* src = base + (size_t)((C + 1) * 64) * ROWW;
#pragma unroll
    for (int k = 0; k < 32; ++k) Pt[k] = src[(2 * k + hf) * ROWW + lw];
  }
  // scalar serial chain over the chunk's diagonal tile
  const u64* dgc = dg + C * 64;
  u64 cl = cur;
#pragma unroll
  for (int ii = 0; ii < 64; ++ii) {
    u64 D = dgc[ii];                       // uniform -> s_load (merged x16)
    u64 t = ((~cl & vb) >> ii) & 1ULL;
    cl |= t ? D : 0ULL;                    // s_cselect_b64 + s_or_b64
  }
  u64 keepb = vb & ~cl;
  // fold kept rows into distributed rem (register-resident VALU)
#pragma unroll
  for (int k = 0; k < 32; ++k) {
    u32 two = (u32)((keepb >> (2 * k)) & 3ULL);   // scalar 2-bit
    u32 bit = (two >> hf) & 1u;                   // lane-half selects its row bit
    u64 km = 0ULL - (u64)bit;
    rem |= Rt[k] & km;
  }
  if (lane == 0) kbits_s[C] = keepb;
  // seed next chunk's removed word via readlanes (word C+1 = even|odd halves)
  {
    int nw = (C + 1) & 31;
    u32 rlo = (u32)rem, rhi = (u32)(rem >> 32);
    u32 a0 = (u32)__builtin_amdgcn_readlane((int)rlo, nw);
    u32 a1 = (u32)__builtin_amdgcn_readlane((int)rhi, nw);
    u32 b0 = (u32)__builtin_amdgcn_readlane((int)rlo, nw + 32);
    u32 b1 = (u32)__builtin_amdgcn_readlane((int)rhi, nw + 32);
    cur = ((u64)(a0 | b0)) | (((u64)(a1 | b1)) << 32);
  }
}

__global__ __launch_bounds__(64, 1) void seq_nms_kernel(
    const u64* __restrict__ mask, const u64* __restrict__ diag,
    const int* __restrict__ valid,
    const float4* __restrict__ boxes, const float* __restrict__ scores,
    float* __restrict__ out) {
  int b = blockIdx.x;
  int lane = threadIdx.x;
  int lw = lane & 31, hf = lane >> 5;
  __shared__ u64 kbits_s[NCHUNK];
  __shared__ int chunkoff[NCHUNK];
  __shared__ int keeplist[PRE];
  __shared__ int Ksh;

  // preload valid values into VGPRs (ballot per chunk happens in-loop)
  int vreg[NCHUNK];
#pragma unroll
  for (int c = 0; c < NCHUNK; ++c) {
    int q = c * 64 + lane;
    vreg[c] = (q < PRE) ? valid[b * RSTRIDE + q] : 0;
  }

  const u64* base = mask + (size_t)b * RSTRIDE * ROWW;
  const u64* dg = diag + (size_t)b * RSTRIDE;
  u64 A[32], Bt[32];
#pragma unroll
  for (int k = 0; k < 32; ++k) A[k] = base[(2 * k + hf) * ROWW + lw];

  u64 rem = 0ULL, cur = 0ULL;
#define NMS_STEP2(CC) \
  nms_chunk<CC>(base, dg, A, Bt, __ballot(vreg[CC] != 0), rem, cur, kbits_s, lane, lw, hf); \
  nms_chunk<CC + 1>(base, dg, Bt, A, __ballot(vreg[CC + 1] != 0), rem, cur, kbits_s, lane, lw, hf);
  NMS_STEP2(0)  NMS_STEP2(2)  NMS_STEP2(4)  NMS_STEP2(6)
  NMS_STEP2(8)  NMS_STEP2(10) NMS_STEP2(12) NMS_STEP2(14)
  NMS_STEP2(16) NMS_STEP2(18) NMS_STEP2(20) NMS_STEP2(22)
  NMS_STEP2(24) NMS_STEP2(26) NMS_STEP2(28) NMS_STEP2(30)
#undef NMS_STEP2
  __syncthreads();

  // compact keep list: wave prefix-scan of per-chunk popcounts
  {
    int pc = (lane < NCHUNK) ? (int)__popcll(kbits_s[lane]) : 0;
    int inc = pc;
    for (int d = 1; d < 64; d <<= 1) {
      int n = __shfl_up(inc, d, 64);
      if (lane >= d) inc += n;
    }
    if (lane < NCHUNK) chunkoff[lane] = inc - pc;   // exclusive
    if (lane == NCHUNK - 1) Ksh = inc;
  }
  __syncthreads();
  for (int c = 0; c < NCHUNK; ++c) {
    u64 word = kbits_s[c];
    if ((word >> lane) & 1ULL) {
      int rank = (int)__popcll(word & ((1ULL << lane) - 1ULL));
      keeplist[chunkoff[c] + rank] = c * 64 + lane;
    }
  }
  __syncthreads();
  int K = Ksh;

  float* rois = out;
  float* probs = out + (size_t)BN * POST * 5;
  for (int r = lane; r < POST; r += 64) {
    float x1 = 0.f, y1 = 0.f, x2 = 0.f, y2 = 0.f, pr = 0.f;
    if (r < K) {
      int i = keeplist[r];
      float4 bb = boxes[b * RSTRIDE + i];
      x1 = bb.x; y1 = bb.y; x2 = bb.z; y2 = bb.w;
      pr = scores[b * RSTRIDE + i];
    }
    size_t ro = (size_t)(b * POST + r) * 5;
    rois[ro + 0] = (float)b;
    rois[ro + 1] = x1; rois[ro + 2] = y1; rois[ro + 3] = x2; rois[ro + 4] = y2;
    probs[b * POST + r] = pr;
  }
}

extern "C" void kernel_launch(void* const* d_in, const int* in_sizes, int n_in,
                              void* d_out, int out_size, void* d_ws, size_t ws_size,
                              hipStream_t stream) {
  const float* cls    = (const float*)d_in[0];
  const float* bbox   = (const float*)d_in[1];
  const float* iminfo = (const float*)d_in[2];
  const float* anch   = (const float*)d_in[3];
  char* ws = (char*)d_ws;
  u32* h1    = (u32*)(ws + OFF_H1);
  u32* h2    = (u32*)(ws + OFF_H2);
  u32* cstar = (u32*)(ws + OFF_CSTAR);
  u32* ccnt  = (u32*)(ws + OFF_CCNT);
  u32* thr   = (u32*)(ws + OFF_THR);
  u64* cand  = (u64*)(ws + OFF_CAND);
  float4* boxes = (float4*)(ws + OFF_BOX);
  float* scores = (float*)(ws + OFF_SCORE);
  int* valid    = (int*)(ws + OFF_VALID);
  u64* mask     = (u64*)(ws + OFF_MASK);
  u64* diag     = (u64*)(ws + OFF_DIAG);
  float* out = (float*)d_out;

  zero_kernel<<<(ZERO_WORDS + 255) / 256, 256, 0, stream>>>((u32*)ws, ZERO_WORDS);
  hist1_kernel<<<dim3(HBLK, BN), 256, 0, stream>>>(cls, h1);
  coarse_kernel<<<BN, 256, 0, stream>>>(h1, cstar);
  hist2_kernel<<<dim3(HBLK, BN), 256, 0, stream>>>(cls, cstar, h2);
  fine_kernel<<<BN, 256, 0, stream>>>(h2, cstar, thr);
  gather_kernel<<<NTOT / 256, 256, 0, stream>>>(cls, thr, ccnt, cand);
  sort_transform_kernel<<<BN, 1024, 0, stream>>>(cand, ccnt, bbox, iminfo, anch,
                                                 boxes, scores, valid);
  nms_mask_kernel<<<dim3(32, 32, BN), 64, 0, stream>>>(boxes, mask, diag);
  seq_nms_kernel<<<BN, 64, 0, stream>>>(mask, diag, valid, boxes, scores, out);
}

// Round 9
// 353.091 us; speedup vs baseline: 1.0208x; 1.0208x over previous
//
#include <hip/hip_runtime.h>
#include <hip/hip_bf16.h>
#include <math.h>

#define BN 8
#define AN 15
#define HH 100
#define WW 168
#define HW (HH*WW)           // 16800
#define NPI (AN*HW)          // 252000 scores per image
#define NTOT (BN*NPI)        // 2016000
#define PRE 2000
#define POST 1000
#define CAP 4096             // candidate buffer per image (threshold-bucket bound ~3000)
#define ROWW 32              // u64 words per NMS mask row (2000 bits -> 32 words)
#define NCHUNK 32            // ceil(PRE/64)
#define RSTRIDE 2048         // padded per-image row stride
#define EPB 4096             // elements per hist block
#define HBLK 62              // ceil(NPI/EPB)

typedef unsigned int u32;
typedef unsigned long long u64;

// ---- workspace layout (bytes) ----
#define OFF_H1     0            // 8*256*4 = 8192
#define OFF_H2     8192         // 8192
#define OFF_CSTAR  16384        // 8*128 = 1024 (cstar[b*32], base[b*32+1])
#define OFF_CCNT   17408        // 1024
#define OFF_THR    18432        // 1024
#define OFF_CAND   19456        // 8*4096*8 = 262144
#define OFF_BOX    281600       // 8*2048*16 = 262144
#define OFF_SCORE  543744       // 65536
#define OFF_VALID  609280       // 65536
#define OFF_MASK   674816       // 8*2048*32*8 = 4194304
#define OFF_DIAG   4869120      // 8*2048*8 = 131072 (packed diagonal words)
#define ZERO_WORDS ((OFF_CAND) / 4)   // only hist/counters need zeroing

__device__ __forceinline__ u32 fmono(float s) {
  u32 u = __float_as_uint(s);
  return (u & 0x80000000u) ? ~u : (u | 0x80000000u);
}
__device__ __forceinline__ float funmono(u32 m) {
  u32 u = (m & 0x80000000u) ? (m ^ 0x80000000u) : ~m;
  return __uint_as_float(u);
}
__device__ __forceinline__ float areaf(float4 bx) {
  return __fmul_rn(__fadd_rn(__fsub_rn(bx.z, bx.x), 1.0f),
                   __fadd_rn(__fsub_rn(bx.w, bx.y), 1.0f));
}

__global__ void zero_kernel(u32* p, int n) {
  int i = blockIdx.x * blockDim.x + threadIdx.x;
  if (i < n) p[i] = 0u;
}

// phase-1 histogram: 256 coarse buckets (m>>24), LDS-privatized 4-way
__global__ __launch_bounds__(256) void hist1_kernel(const float* __restrict__ cls,
                                                    u32* __restrict__ h1) {
  __shared__ u32 lh[1024];   // 4 copies x 256 buckets
  int b = blockIdx.y;
  int t = threadIdx.x;
  for (int q = t; q < 1024; q += 256) lh[q] = 0u;
  __syncthreads();
  int start = blockIdx.x * EPB;
  int end = min(start + EPB, NPI);
  const float* p = cls + (size_t)b * NPI;
  u32 copy = ((u32)t & 3u) << 8;
  for (int i = start + t; i < end; i += 256) {
    u32 m = fmono(p[i]);
    atomicAdd(&lh[copy | (m >> 24)], 1u);
  }
  __syncthreads();
  u32 s = lh[t] + lh[t + 256] + lh[t + 512] + lh[t + 768];
  if (s) atomicAdd(&h1[(b << 8) + t], s);
}

// pick coarse bucket c*: suffix scan of 256 coarse counts
__global__ __launch_bounds__(256) void coarse_kernel(const u32* __restrict__ h1,
                                                     u32* __restrict__ cstar) {
  int b = blockIdx.x;
  int t = threadIdx.x;
  __shared__ u32 sfx[256];
  sfx[t] = h1[(b << 8) + t];
  __syncthreads();
  for (int d = 1; d < 256; d <<= 1) {
    u32 add = (t + d < 256) ? sfx[t + d] : 0u;
    __syncthreads();
    sfx[t] += add;
    __syncthreads();
  }
  if (t == 0 && sfx[0] < (u32)PRE) { cstar[b * 32] = 0u; cstar[b * 32 + 1] = sfx[1]; }
  if (sfx[t] >= (u32)PRE && (t == 255 || sfx[t + 1] < (u32)PRE)) {
    cstar[b * 32] = (u32)t;
    cstar[b * 32 + 1] = (t == 255) ? 0u : sfx[t + 1];   // count strictly above c*
  }
}

// phase-2 histogram: 256 fine buckets ((m>>16)&0xFF), filtered to m>>24==c*
__global__ __launch_bounds__(256) void hist2_kernel(const float* __restrict__ cls,
                                                    const u32* __restrict__ cstar,
                                                    u32* __restrict__ h2) {
  __shared__ u32 lh[256];
  int b = blockIdx.y;
  int t = threadIdx.x;
  lh[t] = 0u;
  __syncthreads();
  u32 cs = cstar[b * 32];
  int start = blockIdx.x * EPB;
  int end = min(start + EPB, NPI);
  const float* p = cls + (size_t)b * NPI;
  for (int i = start + t; i < end; i += 256) {
    u32 m = fmono(p[i]);
    if ((m >> 24) == cs) atomicAdd(&lh[(m >> 16) & 0xFFu], 1u);
  }
  __syncthreads();
  if (lh[t]) atomicAdd(&h2[(b << 8) + t], lh[t]);
}

// final 16-bit threshold: thr16 = (c*<<8) | k*, largest k with base+sfx[k] >= PRE
__global__ __launch_bounds__(256) void fine_kernel(const u32* __restrict__ h2,
                                                   const u32* __restrict__ cstar,
                                                   u32* __restrict__ thr) {
  int b = blockIdx.x;
  int t = threadIdx.x;
  __shared__ u32 sfx[256];
  sfx[t] = h2[(b << 8) + t];
  __syncthreads();
  for (int d = 1; d < 256; d <<= 1) {
    u32 add = (t + d < 256) ? sfx[t + d] : 0u;
    __syncthreads();
    sfx[t] += add;
    __syncthreads();
  }
  u32 cs = cstar[b * 32], base = cstar[b * 32 + 1];
  if (t == 0 && base + sfx[0] < (u32)PRE) thr[b * 32] = (cs << 8);
  if (base + sfx[t] >= (u32)PRE && (t == 255 || base + sfx[t + 1] < (u32)PRE))
    thr[b * 32] = (cs << 8) | (u32)t;
}

// wave-aggregated gather: one atomic per wave with >=1 candidate
__global__ void gather_kernel(const float* __restrict__ cls, const u32* __restrict__ thr,
                              u32* __restrict__ ccnt, u64* __restrict__ cand) {
  int tid = blockIdx.x * blockDim.x + threadIdx.x;   // grid exactly covers NTOT
  int b = tid / NPI;
  int r = tid - b * NPI;
  u32 m = fmono(cls[tid]);
  bool pass = (m >> 16) >= thr[b * 32];
  int lane = threadIdx.x & 63;
  int b0 = __shfl(b, 0, 64);
  bool uni = (__ballot(b != b0) == 0ULL);
  u32 pos = 0xffffffffu;
  if (uni) {
    u64 bal = __ballot(pass);
    if (bal) {
      int leader = __ffsll((long long)bal) - 1;
      u32 base = 0;
      if (lane == leader) base = atomicAdd(&ccnt[b * 32], (u32)__popcll(bal));
      base = __shfl(base, leader, 64);
      if (pass) pos = base + (u32)__popcll(bal & ((1ULL << lane) - 1ULL));
    }
  } else if (pass) {
    pos = atomicAdd(&ccnt[b * 32], 1u);
  }
  if (pass && pos < CAP) {
    int a  = r / HW;
    int hw = r - a * HW;
    u32 i  = (u32)(hw * AN + a);   // transposed flat index (h*W + w)*A + a
    cand[(size_t)b * CAP + pos] = ((u64)m << 32) | (u32)(~i);
  }
}

__global__ __launch_bounds__(1024) void sort_transform_kernel(
    const u64* __restrict__ cand, const u32* __restrict__ ccnt,
    const float* __restrict__ bbox, const float* __restrict__ iminfo,
    const float* __restrict__ anch,
    float4* __restrict__ boxes, float* __restrict__ scores, int* __restrict__ valid) {
  __shared__ u64 keys[CAP];   // 32 KB
  int b = blockIdx.x;
  int t = threadIdx.x;
  u32 cnt = ccnt[b * 32];
  if (cnt > CAP) cnt = CAP;
  for (int q = t; q < CAP; q += 1024) keys[q] = (q < (int)cnt) ? cand[(size_t)b * CAP + q] : 0ULL;
  __syncthreads();
  // bitonic sort, descending
  for (u32 k = 2; k <= CAP; k <<= 1) {
    for (u32 j = k >> 1; j > 0; j >>= 1) {
      for (int p = 0; p < CAP / 2 / 1024; ++p) {
        u32 idx = (u32)t + (u32)p * 1024u;           // 0..CAP/2-1
        u32 base = ((idx & ~(j - 1)) << 1) | (idx & (j - 1));
        u32 partner = base + j;
        bool up = ((base & k) == 0);
        u64 A = keys[base], B = keys[partner];
        bool sw = up ? (A < B) : (A > B);
        if (sw) { keys[base] = B; keys[partner] = A; }
      }
      __syncthreads();
    }
  }
  // transform the top PRE
  float im_h = iminfo[b * 3 + 0], im_w = iminfo[b * 3 + 1], im_s = iminfo[b * 3 + 2];
  float wmax = __fsub_rn(im_w, 1.0f), hmax = __fsub_rn(im_h, 1.0f);
  float msz = __fmul_rn(0.0f, im_s);
  const float BCLIP = (float)4.135166556742356;  // log(1000/16)
  for (int q = t; q < PRE; q += 1024) {
    u64 key = keys[q];
    u32 i = ~((u32)key);
    // defensive: pad keys (q >= cnt) decode to i >= NPI -> never dereference
    if (q >= (int)cnt || i >= (u32)NPI) {
      boxes[b * RSTRIDE + q] = make_float4(0.f, 0.f, 0.f, 0.f);
      scores[b * RSTRIDE + q] = 0.f;
      valid[b * RSTRIDE + q] = 0;
      continue;
    }
    float sc = funmono((u32)(key >> 32));
    int a = (int)(i % AN);
    int pp = (int)(i / AN);
    int w = pp % WW;
    int h = pp / WW;
    float sx = (float)(w * 8), sy = (float)(h * 8);
    float ax1 = __fadd_rn(anch[a * 4 + 0], sx);
    float ay1 = __fadd_rn(anch[a * 4 + 1], sy);
    float ax2 = __fadd_rn(anch[a * 4 + 2], sx);
    float ay2 = __fadd_rn(anch[a * 4 + 3], sy);
    float wsA = __fadd_rn(__fsub_rn(ax2, ax1), 1.0f);
    float hsA = __fadd_rn(__fsub_rn(ay2, ay1), 1.0f);
    float cx = __fadd_rn(ax1, __fmul_rn(0.5f, wsA));
    float cy = __fadd_rn(ay1, __fmul_rn(0.5f, hsA));
    const float* dp = bbox + ((size_t)b * (4 * AN) + 4 * a) * HW + (size_t)h * WW + w;
    float dx = dp[0], dy = dp[HW], dwv = dp[2 * HW], dhv = dp[3 * HW];
    dwv = fminf(dwv, BCLIP);
    dhv = fminf(dhv, BCLIP);
    float pcx = __fadd_rn(__fmul_rn(dx, wsA), cx);
    float pcy = __fadd_rn(__fmul_rn(dy, hsA), cy);
    float pw = __fmul_rn((float)exp((double)dwv), wsA);
    float ph = __fmul_rn((float)exp((double)dhv), hsA);
    float hpw = __fmul_rn(0.5f, pw), hph = __fmul_rn(0.5f, ph);
    float x1 = __fsub_rn(pcx, hpw);
    float y1 = __fsub_rn(pcy, hph);
    float x2 = __fsub_rn(__fadd_rn(pcx, hpw), 1.0f);
    float y2 = __fsub_rn(__fadd_rn(pcy, hph), 1.0f);
    x1 = fminf(fmaxf(x1, 0.0f), wmax);
    y1 = fminf(fmaxf(y1, 0.0f), hmax);
    x2 = fminf(fmaxf(x2, 0.0f), wmax);
    y2 = fminf(fmaxf(y2, 0.0f), hmax);
    float ws2 = __fadd_rn(__fsub_rn(x2, x1), 1.0f);
    float hs2 = __fadd_rn(__fsub_rn(y2, y1), 1.0f);
    int v = (ws2 >= msz) && (hs2 >= msz) &&
            (__fadd_rn(x1, __fmul_rn(ws2, 0.5f)) < im_w) &&
            (__fadd_rn(y1, __fmul_rn(hs2, 0.5f)) < im_h);
    boxes[b * RSTRIDE + q] = make_float4(x1, y1, x2, y2);
    scores[b * RSTRIDE + q] = sc;
    valid[b * RSTRIDE + q] = v;
  }
}

__global__ __launch_bounds__(64) void nms_mask_kernel(const float4* __restrict__ boxes,
                                                      u64* __restrict__ mask,
                                                      u64* __restrict__ diag) {
  int jb = blockIdx.x, ib = blockIdx.y, b = blockIdx.z;
  if (jb < ib) return;   // upper triangle only (j > i needed)
  int t = threadIdx.x;
  __shared__ float4 jbox[64];
  __shared__ float jarea[64];
  int jbase = jb * 64;
  int jcount = min(64, PRE - jbase);
  if (t < jcount) {
    float4 bj = boxes[b * RSTRIDE + jbase + t];
    jbox[t] = bj;
    jarea[t] = areaf(bj);
  }
  __syncthreads();
  int i = ib * 64 + t;
  if (i >= PRE) return;
  float4 bi = boxes[b * RSTRIDE + i];
  float ai = areaf(bi);
  u64 word = 0ULL;
  for (int jj = 0; jj < jcount; ++jj) {
    int j = jbase + jj;
    if (j <= i) continue;
    float4 bj = jbox[jj];
    float iw = fmaxf(__fadd_rn(__fsub_rn(fminf(bi.z, bj.z), fmaxf(bi.x, bj.x)), 1.0f), 0.0f);
    float ih = fmaxf(__fadd_rn(__fsub_rn(fminf(bi.w, bj.w), fmaxf(bi.y, bj.y)), 1.0f), 0.0f);
    float inter = __fmul_rn(iw, ih);
    float denom = __fsub_rn(__fadd_rn(ai, jarea[jj]), inter);
    float iou = inter / denom;
    if (iou > 0.7f) word |= (1ULL << jj);
  }
  mask[((size_t)(b * RSTRIDE) + i) * ROWW + jb] = word;
  if (jb == ib) diag[(size_t)b * RSTRIDE + i] = word;   // packed diagonal word
}

// ---------------- seq NMS v6: LDS DMA tile + scalar chain ----------------
// R8 postmortem: all scan variants stuck at ~120us because the 16KB/chunk
// tile spilled to scratch (VGPR_Count 96 < 128 needed). v6 holds NO tile in
// registers: global_load_lds width=16 DMA-stages each chunk into a double-
// buffered LDS tile (16 instr/chunk), explicit s_waitcnt vmcnt(16) keeps the
// prefetch in flight while draining the previous chunk. Scan = R8's scalar
// chain on the packed diag buffer. Fold = 64 masked ds_read_b64 (static imm
// offsets, pipelined; lanes L/L+32 broadcast).
__device__ __forceinline__ void stage_chunk(const void* gsrc, void* lds, int lane) {
#pragma unroll
  for (int k = 0; k < 16; ++k) {
    const char* g = (const char*)gsrc + k * 1024 + lane * 16;
    char* l = (char*)lds + k * 1024;   // HW dest = uniform base + lane*16
    __builtin_amdgcn_global_load_lds(
        (const __attribute__((address_space(1))) unsigned int*)g,
        (__attribute__((address_space(3))) unsigned int*)l, 16, 0, 0);
  }
}

__global__ __launch_bounds__(64) void seq_nms_kernel(
    const u64* __restrict__ mask, const u64* __restrict__ diag,
    const int* __restrict__ valid,
    const float4* __restrict__ boxes, const float* __restrict__ scores,
    float* __restrict__ out) {
  int b = blockIdx.x;
  int lane = threadIdx.x;
  int lw = lane & 31;
  __shared__ u64 rowbuf[2][64 * ROWW];   // 2 x 16 KB double buffer
  __shared__ u64 vbuf[NCHUNK];
  __shared__ u64 kbits_s[NCHUNK];
  __shared__ int chunkoff[NCHUNK];
  __shared__ int keeplist[PRE];
  __shared__ int Ksh;

  // precompute per-chunk valid ballots into LDS (unrolled: static v[] index)
  {
    int v[NCHUNK];
#pragma unroll
    for (int c = 0; c < NCHUNK; ++c) {
      int q = c * 64 + lane;
      v[c] = (q < PRE) ? valid[b * RSTRIDE + q] : 0;
    }
#pragma unroll
    for (int c = 0; c < NCHUNK; ++c) {
      u64 bl = __ballot(v[c] != 0);
      if (lane == 0) vbuf[c] = bl;
    }
  }

  const u64* base = mask + (size_t)b * RSTRIDE * ROWW;
  const u64* dg = diag + (size_t)b * RSTRIDE;

  stage_chunk(base, rowbuf[0], lane);     // chunk 0

  u64 rem = 0ULL, cur = 0ULL;
  for (int c = 0; c < NCHUNK; ++c) {
    // prefetch next chunk (independent; overlaps everything below)
    if (c + 1 < NCHUNK) stage_chunk(base + (size_t)(c + 1) * 64 * ROWW,
                                    rowbuf[(c + 1) & 1], lane);
    // wave-uniform valid mask, rescalarized
    u64 vbv = vbuf[c];
    u32 vlo = (u32)__builtin_amdgcn_readfirstlane((int)(u32)vbv);
    u32 vhi = (u32)__builtin_amdgcn_readfirstlane((int)(u32)(vbv >> 32));
    u64 vb = ((u64)vhi << 32) | vlo;
    // scalar serial chain over the chunk's diagonal words
    const u64* dgc = dg + c * 64;
    u64 cl = cur;
#pragma unroll
    for (int ii = 0; ii < 64; ++ii) {
      u64 D = dgc[ii];                     // uniform -> s_load (merged x16)
      u64 t = ((~cl & vb) >> ii) & 1ULL;
      cl |= t ? D : 0ULL;                  // s_cselect_b64 + s_or_b64
    }
    u64 keepb = vb & ~cl;
    // drain previous chunk's staging; keep the 16 prefetch loads in flight
    if (c + 1 < NCHUNK) __builtin_amdgcn_s_waitcnt(0x4F70);   // vmcnt(16)
    else                __builtin_amdgcn_s_waitcnt(0x0F70);   // vmcnt(0)
    // fold kept rows into distributed rem (64 masked ds_read_b64, pipelined)
    const u64* rb = rowbuf[c & 1];
#pragma unroll
    for (int ii = 0; ii < 64; ++ii) {
      u64 km = ((keepb >> ii) & 1ULL) ? ~0ULL : 0ULL;
      rem |= rb[ii * ROWW + lw] & km;
    }
    if (lane == 0) kbits_s[c] = keepb;
    // seed next chunk's removed word (lanes nw and nw+32 hold identical data)
    int nw = (c + 1) & 31;
    u32 a0 = (u32)__builtin_amdgcn_readlane((int)(u32)rem, nw);
    u32 a1 = (u32)__builtin_amdgcn_readlane((int)(u32)(rem >> 32), nw);
    u32 b0 = (u32)__builtin_amdgcn_readlane((int)(u32)rem, nw + 32);
    u32 b1 = (u32)__builtin_amdgcn_readlane((int)(u32)(rem >> 32), nw + 32);
    cur = ((u64)(a0 | b0)) | (((u64)(a1 | b1)) << 32);
  }
  __syncthreads();

  // compact keep list: wave prefix-scan of per-chunk popcounts
  {
    int pc = (lane < NCHUNK) ? (int)__popcll(kbits_s[lane]) : 0;
    int inc = pc;
    for (int d = 1; d < 64; d <<= 1) {
      int n = __shfl_up(inc, d, 64);
      if (lane >= d) inc += n;
    }
    if (lane < NCHUNK) chunkoff[lane] = inc - pc;   // exclusive
    if (lane == NCHUNK - 1) Ksh = inc;
  }
  __syncthreads();
  for (int c = 0; c < NCHUNK; ++c) {
    u64 word = kbits_s[c];
    if ((word >> lane) & 1ULL) {
      int rank = (int)__popcll(word & ((1ULL << lane) - 1ULL));
      keeplist[chunkoff[c] + rank] = c * 64 + lane;
    }
  }
  __syncthreads();
  int K = Ksh;

  float* rois = out;
  float* probs = out + (size_t)BN * POST * 5;
  for (int r = lane; r < POST; r += 64) {
    float x1 = 0.f, y1 = 0.f, x2 = 0.f, y2 = 0.f, pr = 0.f;
    if (r < K) {
      int i = keeplist[r];
      float4 bb = boxes[b * RSTRIDE + i];
      x1 = bb.x; y1 = bb.y; x2 = bb.z; y2 = bb.w;
      pr = scores[b * RSTRIDE + i];
    }
    size_t ro = (size_t)(b * POST + r) * 5;
    rois[ro + 0] = (float)b;
    rois[ro + 1] = x1; rois[ro + 2] = y1; rois[ro + 3] = x2; rois[ro + 4] = y2;
    probs[b * POST + r] = pr;
  }
}

extern "C" void kernel_launch(void* const* d_in, const int* in_sizes, int n_in,
                              void* d_out, int out_size, void* d_ws, size_t ws_size,
                              hipStream_t stream) {
  const float* cls    = (const float*)d_in[0];
  const float* bbox   = (const float*)d_in[1];
  const float* iminfo = (const float*)d_in[2];
  const float* anch   = (const float*)d_in[3];
  char* ws = (char*)d_ws;
  u32* h1    = (u32*)(ws + OFF_H1);
  u32* h2    = (u32*)(ws + OFF_H2);
  u32* cstar = (u32*)(ws + OFF_CSTAR);
  u32* ccnt  = (u32*)(ws + OFF_CCNT);
  u32* thr   = (u32*)(ws + OFF_THR);
  u64* cand  = (u64*)(ws + OFF_CAND);
  float4* boxes = (float4*)(ws + OFF_BOX);
  float* scores = (float*)(ws + OFF_SCORE);
  int* valid    = (int*)(ws + OFF_VALID);
  u64* mask     = (u64*)(ws + OFF_MASK);
  u64* diag     = (u64*)(ws + OFF_DIAG);
  float* out = (float*)d_out;

  zero_kernel<<<(ZERO_WORDS + 255) / 256, 256, 0, stream>>>((u32*)ws, ZERO_WORDS);
  hist1_kernel<<<dim3(HBLK, BN), 256, 0, stream>>>(cls, h1);
  coarse_kernel<<<BN, 256, 0, stream>>>(h1, cstar);
  hist2_kernel<<<dim3(HBLK, BN), 256, 0, stream>>>(cls, cstar, h2);
  fine_kernel<<<BN, 256, 0, stream>>>(h2, cstar, thr);
  gather_kernel<<<NTOT / 256, 256, 0, stream>>>(cls, thr, ccnt, cand);
  sort_transform_kernel<<<BN, 1024, 0, stream>>>(cand, ccnt, bbox, iminfo, anch,
                                                 boxes, scores, valid);
  nms_mask_kernel<<<dim3(32, 32, BN), 64, 0, stream>>>(boxes, mask, diag);
  seq_nms_kernel<<<BN, 64, 0, stream>>>(mask, diag, valid, boxes, scores, out);
}